// Round 10
// baseline (7428.619 us; speedup 1.0000x reference)
//
#include <hip/hip_runtime.h>
#include <hip/hip_bf16.h>

#define D_  768
#define B_  1024
#define N_  50000
#define K_  10
#define CH_ 3125
#define NCH_ 16

__device__ __forceinline__ float gelu_f(float x){ return 0.5f*x*(1.0f+erff(x*0.70710678118654752f)); }
__device__ __forceinline__ double gelu_d(double x){ return 0.5*x*(1.0+erf(x*0.707106781186547524400844362105)); }

__device__ __forceinline__ float block_sum(float v, float* sm){
  #pragma unroll
  for (int o=32;o>0;o>>=1) v += __shfl_xor(v,o);
  __syncthreads();
  if ((threadIdx.x&63)==0) sm[threadIdx.x>>6]=v;
  __syncthreads();
  return (sm[0]+sm[1])+(sm[2]+sm[3]);
}
__device__ __forceinline__ double block_sum64(double v, double* sm){
  #pragma unroll
  for (int o=32;o>0;o>>=1) v += __shfl_xor(v,o);
  __syncthreads();
  if ((threadIdx.x&63)==0) sm[threadIdx.x>>6]=v;
  __syncthreads();
  return (sm[0]+sm[1])+(sm[2]+sm[3]);
}

// ============ f64 tiled GEMM: C = A @ W^T (+bias) (×inva×invw) ============
// ASRC: 0 = A f64 ws; 1 = A f32 (d_in).  EPI: 1 adds f32 bias. SCALE: ×inva[r]×invw[n].
template<int ASRC, int EPI, int SCALE>
__global__ __launch_bounds__(256)
void dgemm_k(const void* __restrict__ Ap, const float* __restrict__ Wp, size_t woff,
             const float* __restrict__ biasp, size_t boff, double* __restrict__ Cp,
             const double* __restrict__ inva, const double* __restrict__ invw,
             int M, int N, int Kd, int ldc)
{
  __shared__ double As[16][64];
  __shared__ double Bs[16][64];
  const int t  = threadIdx.x;
  const int tx = t & 15, ty = t >> 4;
  const int row0 = blockIdx.y << 6, col0 = blockIdx.x << 6;
  const int lr = t >> 2, lk = (t & 3) << 2;
  const int ar = row0 + lr;
  const int wn = col0 + lr;
  const float* Wf = Wp + woff;
  double acc[4][4] = {};
  for (int k0 = 0; k0 < Kd; k0 += 16) {
    double av[4], wv[4];
    if (ar < M) {
      if (ASRC==0){
        const double* a = (const double*)Ap + (size_t)ar*Kd + k0 + lk;
        av[0]=a[0]; av[1]=a[1]; av[2]=a[2]; av[3]=a[3];
      } else {
        float4 v = *(const float4*)((const float*)Ap + (size_t)ar*Kd + k0 + lk);
        av[0]=(double)v.x; av[1]=(double)v.y; av[2]=(double)v.z; av[3]=(double)v.w;
      }
    } else { av[0]=av[1]=av[2]=av[3]=0.0; }
    if (wn < N) {
      float4 v = *(const float4*)(Wf + (size_t)wn*Kd + k0 + lk);
      wv[0]=(double)v.x; wv[1]=(double)v.y; wv[2]=(double)v.z; wv[3]=(double)v.w;
    } else { wv[0]=wv[1]=wv[2]=wv[3]=0.0; }
    #pragma unroll
    for (int u=0;u<4;++u){ As[lk+u][lr]=av[u]; Bs[lk+u][lr]=wv[u]; }
    __syncthreads();
    #pragma unroll
    for (int kk=0;kk<16;++kk){
      double aa[4], bb[4];
      #pragma unroll
      for (int u=0;u<4;++u){ aa[u]=As[kk][(ty<<2)+u]; bb[u]=Bs[kk][(tx<<2)+u]; }
      #pragma unroll
      for (int i=0;i<4;++i)
        #pragma unroll
        for (int j=0;j<4;++j)
          acc[i][j] = fma(aa[i], bb[j], acc[i][j]);
    }
    __syncthreads();
  }
  #pragma unroll
  for (int i=0;i<4;++i){
    int r=row0+(ty<<2)+i; if (r>=M) continue;
    double ia = SCALE ? inva[r] : 1.0;
    #pragma unroll
    for (int j=0;j<4;++j){
      int n=col0+(tx<<2)+j; if (n>=N) continue;
      double v=acc[i][j];
      if (EPI) v += (double)(biasp+boff)[n];
      if (SCALE) v = v * ia * invw[n];
      Cp[(size_t)r*ldc+n]=v;
    }
  }
}

// f64 LN + gelu (stage B): y = gelu( LN(x) * g + b )
__global__ __launch_bounds__(256)
void ln64_k(const double* __restrict__ x0, const float* __restrict__ g,
            const float* __restrict__ b, double* __restrict__ y)
{
  __shared__ double sm[4];
  size_t base = (size_t)blockIdx.x * D_;
  double xv[3]; double s=0.0;
  #pragma unroll
  for (int i=0;i<3;++i){ int c=threadIdx.x+(i<<8); xv[i]=x0[base+c]; s+=xv[i]; }
  s = block_sum64(s, sm);
  double m = s*(1.0/768.0);
  double vs=0.0;
  #pragma unroll
  for (int i=0;i<3;++i){ double d=xv[i]-m; vs+=d*d; }
  vs = block_sum64(vs, sm);
  double inv = 1.0/sqrt(vs*(1.0/768.0)+1e-5);
  #pragma unroll
  for (int i=0;i<3;++i){
    int c=threadIdx.x+(i<<8);
    double o=(xv[i]-m)*inv*(double)g[c]+(double)b[c];
    y[base+c]=gelu_d(o);
  }
}

// f64 inverse row norm.  SRC: 0 f64 ws, 1 f32 d_in.
template<int SRC>
__global__ __launch_bounds__(256)
void rnorm64_k(const void* __restrict__ x, double* __restrict__ invn)
{
  __shared__ double sm[4];
  size_t base=(size_t)blockIdx.x*D_;
  double s=0.0;
  for (int i=threadIdx.x;i<D_;i+=256){
    double v = (SRC==0) ? ((const double*)x)[base+i] : (double)((const float*)x)[base+i];
    s=fma(v,v,s);
  }
  s=block_sum64(s,sm);
  if (threadIdx.x==0) invn[blockIdx.x]=1.0/fmax(sqrt(s),1e-12);
}

// per row, per chunk: f64 top-10 (scores pre-scaled cosines)
__global__ __launch_bounds__(256)
void topk10_chunk64_k(const double* __restrict__ simc,
                      double* __restrict__ cand_sc, int* __restrict__ cand_id,
                      int off, int chunk, int cn, int ldc)
{
  __shared__ double sc_s[2560];
  __shared__ int    id_s[2560];
  int b=blockIdx.x, t=threadIdx.x;
  const double* rowp = simc + (size_t)b*ldc;
  double ls[10]; int li[10];
  #pragma unroll
  for (int k=0;k<10;++k){ ls[k]=-1e300; li[k]=0x7fffffff; }
  for (int j=t;j<cn;j+=256){
    double sc = rowp[j];
    int id = off + j;
    if (sc > ls[9] || (sc == ls[9] && id < li[9])){
      int p=9;
      while (p>0 && (ls[p-1]<sc || (ls[p-1]==sc && li[p-1]>id))){
        ls[p]=ls[p-1]; li[p]=li[p-1]; --p;
      }
      ls[p]=sc; li[p]=id;
    }
  }
  #pragma unroll
  for (int k=0;k<10;++k){ sc_s[t*10+k]=ls[k]; id_s[t*10+k]=li[k]; }
  __syncthreads();
  if (t==0){
    double gs[10]; int gi[10];
    #pragma unroll
    for (int k=0;k<10;++k){ gs[k]=-1e300; gi[k]=0x7fffffff; }
    for (int p=0;p<2560;p+=10){
      for (int k=0;k<10;++k){
        double s=sc_s[p+k]; int id=id_s[p+k];
        bool better9 = (s>gs[9]) || (s==gs[9] && id<gi[9]);
        if (!better9) break;
        int q=9;
        while (q>0 && (gs[q-1]<s || (gs[q-1]==s && gi[q-1]>id))){
          gs[q]=gs[q-1]; gi[q]=gi[q-1]; --q;
        }
        gs[q]=s; gi[q]=id;
      }
    }
    #pragma unroll
    for (int k=0;k<10;++k){
      cand_sc[((size_t)b*NCH_+chunk)*10+k]=gs[k];
      cand_id[((size_t)b*NCH_+chunk)*10+k]=gi[k];
    }
  }
}

__global__ __launch_bounds__(256)
void topk_final64_k(const double* __restrict__ cand_sc, const int* __restrict__ cand_id,
                    int* __restrict__ run_id)
{
  int r = blockIdx.x*256 + threadIdx.x;
  if (r >= B_) return;
  double gs[10]; int gi[10];
  #pragma unroll
  for (int k=0;k<10;++k){ gs[k]=-1e300; gi[k]=0x7fffffff; }
  for (int i=0;i<NCH_*10;++i){
    double s = cand_sc[(size_t)r*NCH_*10 + i];
    int  id = cand_id[(size_t)r*NCH_*10 + i];
    bool better9 = (s>gs[9]) || (s==gs[9] && id<gi[9]);
    if (!better9) continue;
    int q=9;
    while (q>0 && (gs[q-1]<s || (gs[q-1]==s && gi[q-1]>id))){
      gs[q]=gs[q-1]; gi[q]=gi[q-1]; --q;
    }
    gs[q]=s; gi[q]=id;
  }
  #pragma unroll
  for (int k=0;k<10;++k) run_id[r*10+k]=gi[k];
}

__global__ void prep64_k(const float* __restrict__ vis, double* __restrict__ fusedin)
{
  int i = blockIdx.x*256+threadIdx.x;
  if (i >= B_*D_) return;
  int r=i/D_, c=i-r*D_;
  fusedin[(size_t)r*(2*D_)+c]=(double)vis[i];
}

// ============ f32 tiled GEMM (residual stream / m4 / heads) ============
// ATY: 0 = A ws f32; 2 = A d_in f32; 3 = A d_in f32 with row gather.
template<int ATY, int EPI>
__global__ __launch_bounds__(256)
void gemm_k(const float* __restrict__ Ap, const int* __restrict__ ridx,
            const float* __restrict__ Wp, size_t woff,
            const float* __restrict__ biasp, size_t boff, float* __restrict__ Cp,
            int M, int N, int Kd, int ldc)
{
  __shared__ __align__(16) float As[16][64];
  __shared__ __align__(16) float Bs[16][64];
  const int t  = threadIdx.x;
  const int tx = t & 15, ty = t >> 4;
  const int row0 = blockIdx.y << 6, col0 = blockIdx.x << 6;
  const int lr = t >> 2, lk = (t & 3) << 2;
  const int ar = row0 + lr;
  const int wn = col0 + lr;
  const float* Wf = Wp + woff;
  float acc[4][4] = {};
  int arow = ar;
  if (ATY==3 && ar < M){
    arow = ridx[ar];
    if ((unsigned)arow >= (unsigned)N_) arow = 0;
  }
  for (int k0 = 0; k0 < Kd; k0 += 16) {
    float av[4], wv[4];
    if (ar < M) {
      float4 v = *(const float4*)(Ap + (size_t)arow*Kd + k0 + lk);
      av[0]=v.x; av[1]=v.y; av[2]=v.z; av[3]=v.w;
    } else { av[0]=av[1]=av[2]=av[3]=0.f; }
    if (wn < N) {
      float4 v = *(const float4*)(Wf + (size_t)wn*Kd + k0 + lk);
      wv[0]=v.x; wv[1]=v.y; wv[2]=v.z; wv[3]=v.w;
    } else { wv[0]=wv[1]=wv[2]=wv[3]=0.f; }
    #pragma unroll
    for (int u=0;u<4;++u){ As[lk+u][lr]=av[u]; Bs[lk+u][lr]=wv[u]; }
    __syncthreads();
    #pragma unroll
    for (int kk=0;kk<16;++kk){
      float4 a4 = *(const float4*)&As[kk][ty<<2];
      float4 b4 = *(const float4*)&Bs[kk][tx<<2];
      float aa[4]={a4.x,a4.y,a4.z,a4.w};
      float bb[4]={b4.x,b4.y,b4.z,b4.w};
      #pragma unroll
      for (int i=0;i<4;++i)
        #pragma unroll
        for (int j=0;j<4;++j)
          acc[i][j] = fmaf(aa[i], bb[j], acc[i][j]);
    }
    __syncthreads();
  }
  float bv[4];
  #pragma unroll
  for (int j=0;j<4;++j){
    int n=col0+(tx<<2)+j;
    bv[j] = (EPI>=1 && n<N) ? (biasp+boff)[n] : 0.f;
  }
  #pragma unroll
  for (int i=0;i<4;++i){
    int r=row0+(ty<<2)+i; if (r>=M) continue;
    #pragma unroll
    for (int j=0;j<4;++j){
      int n=col0+(tx<<2)+j; if (n>=N) continue;
      float v=acc[i][j]+bv[j];
      if (EPI==2) v=gelu_f(v);
      Cp[(size_t)r*ldc+n]=v;
    }
  }
}

// f32 LN: y = LN(x0 + res) * g + b
template<int RES>
__global__ __launch_bounds__(256)
void ln_k(const float* __restrict__ x0, const float* __restrict__ resf,
          const float* __restrict__ resb,
          const float* __restrict__ g, const float* __restrict__ b, size_t gboff,
          float* __restrict__ y)
{
  __shared__ float sm[4];
  size_t base = (size_t)blockIdx.x * D_;
  float xv[3]; float s=0.f;
  #pragma unroll
  for (int i=0;i<3;++i){
    int c=threadIdx.x+(i<<8);
    float tv=x0[base+c];
    if (RES==1) tv+=resf[base+c];
    if (RES==2) tv+=resb[base+c];
    xv[i]=tv; s+=tv;
  }
  s = block_sum(s, sm);
  float m = s*(1.0f/768.0f);
  float vs=0.f;
  #pragma unroll
  for (int i=0;i<3;++i){ float d=xv[i]-m; vs+=d*d; }
  vs = block_sum(vs, sm);
  float inv = rsqrtf(vs*(1.0f/768.0f)+1e-5f);
  #pragma unroll
  for (int i=0;i<3;++i){
    int c=threadIdx.x+(i<<8);
    y[base+c]=(xv[i]-m)*inv*(g+gboff)[c]+(b+gboff)[c];
  }
}

__global__ void add_k(const float* __restrict__ a, const float* __restrict__ b, float* __restrict__ c, int n)
{ int i=blockIdx.x*256+threadIdx.x; if (i<n) c[i]=a[i]+b[i]; }

// m4 attention: one thread per (b,h), f32.
__global__ __launch_bounds__(64)
void attn2_k(const float* __restrict__ qh, const float* __restrict__ kh,
             const float* __restrict__ vh, float* __restrict__ o)
{
  int idx = blockIdx.x*64 + threadIdx.x;
  if (idx >= B_*8) return;
  int b = idx >> 3, h = idx & 7;
  const float* q = qh + (size_t)b*D_ + h*96;
  float p[10];
  float mx = -1e30f;
  for (int j=0;j<10;++j){
    const float* kr = kh + ((size_t)(b*10+j))*D_ + h*96;
    float acc=0.f;
    for (int d=0;d<96;++d) acc = fmaf(q[d], kr[d], acc);
    p[j] = acc * 0.10206207261596575f;
    mx = fmaxf(mx, p[j]);
  }
  float sum=0.f;
  for (int j=0;j<10;++j){ p[j]=expf(p[j]-mx); sum+=p[j]; }
  float inv=1.0f/sum;
  for (int d=0;d<96;++d){
    float acc=0.f;
    for (int j=0;j<10;++j) acc = fmaf(p[j]*inv, vh[((size_t)(b*10+j))*D_ + h*96 + d], acc);
    o[(size_t)b*D_ + h*96 + d] = acc;
  }
}

extern "C" void kernel_launch(void* const* d_in, const int* in_sizes, int n_in,
                              void* d_out, int out_size, void* d_ws, size_t ws_size,
                              hipStream_t stream)
{
  const float* vis      = (const float*)d_in[0];
  const float* txt      = (const float*)d_in[1];
  const float* ans      = (const float*)d_in[2];
  const float* vqa_in_w = (const float*)d_in[3];
  const float* vqa_in_b = (const float*)d_in[4];
  const float* vqa_out_w= (const float*)d_in[5];
  const float* vqa_out_b= (const float*)d_in[6];
  const float* fproj_w  = (const float*)d_in[7];
  const float* fproj_b  = (const float*)d_in[8];
  const float* fln_g    = (const float*)d_in[9];
  const float* fln_b    = (const float*)d_in[10];
  const float* sim_w    = (const float*)d_in[11];
  const float* sim_b    = (const float*)d_in[12];
  const float* m_in_w   = (const float*)d_in[13];
  const float* m_in_b   = (const float*)d_in[14];
  const float* m_out_w  = (const float*)d_in[15];
  const float* m_out_b  = (const float*)d_in[16];
  const float* ffn_w1   = (const float*)d_in[17];
  const float* ffn_b1   = (const float*)d_in[18];
  const float* ffn_w2   = (const float*)d_in[19];
  const float* ffn_b2   = (const float*)d_in[20];
  const float* ln_g     = (const float*)d_in[21];
  const float* ln_b     = (const float*)d_in[22];
  const float* outp_w   = (const float*)d_in[23];
  const float* outp_b   = (const float*)d_in[24];
  const float* open_w1  = (const float*)d_in[25];
  const float* open_b1  = (const float*)d_in[26];
  const float* open_w2  = (const float*)d_in[27];
  const float* open_b2  = (const float*)d_in[28];
  (void)n_in; (void)out_size;

  if (in_sizes[0]!=B_*D_) return;
  if (in_sizes[1]!=B_*D_) return;
  if (in_sizes[2]!=N_*D_) return;
  if (in_sizes[3]!=3*D_*D_) return;
  if (in_sizes[4]!=3*D_) return;
  if (in_sizes[5]!=D_*D_) return;
  if (in_sizes[7]!=D_*2*D_) return;
  if (in_sizes[9]!=D_) return;
  if (in_sizes[13]!=5*3*D_*D_) return;
  if (in_sizes[14]!=5*3*D_) return;
  if (in_sizes[15]!=5*D_*D_) return;
  if (in_sizes[17]!=4*D_*D_) return;
  if (in_sizes[19]!=4*D_*D_) return;
  if (in_sizes[21]!=4*D_) return;
  if (in_sizes[23]!=D_*D_) return;
  if (in_sizes[25]!=D_*D_) return;
  if (in_sizes[27]!=N_*D_) return;

  const size_t MBc = (size_t)1<<20;
  if (ws_size < 84*MBc) return;
  char* base = (char*)d_ws;
  // ---- phase 1 (f64 selection) overlays [0,62M) ----
  double* attn_v64 = (double*)(base + 0);        // [0,6M)
  double* fusedin64= (double*)(base + 6*MBc);    // [6,18M)
  double* ta64     = (double*)(base + 18*MBc);   // [18,24M)
  double* fused64  = (double*)(base + 24*MBc);   // [24,30M)
  double* fproj64  = (double*)(base + 30*MBc);   // [30,36M)
  double* sim64    = (double*)(base + 36*MBc);   // [36,61.6M)
  // ---- phase 2 (f32) overlays [0,78M) (phase-1 regions dead) ----
  float* kh   = (float*)(base + 0);              // [0,30M)   m4
  float* vh   = (float*)(base + 30*MBc);         // [30,60M)  m4
  float* h1   = (float*)(base + 0);              // [0,12M)   FFN (kh dead)
  float* t1   = (float*)(base + 60*MBc);         // [60,63M)  m1->m2
  float* qh   = (float*)(base + 60*MBc);         // m4 (t1 dead)
  float* g1   = (float*)(base + 60*MBc);         // heads (qh dead)
  float* ta   = (float*)(base + 63*MBc);
  float* tb   = (float*)(base + 66*MBc);
  float* tc   = (float*)(base + 69*MBc);         // m3 temp
  float* fz0  = (float*)(base + 69*MBc);         // after tc dead
  float* td   = (float*)(base + 72*MBc);
  float* fz   = (float*)(base + 72*MBc);         // after td dead
  float* v1   = (float*)(base + 75*MBc);         // m0->m3
  float* o4   = (float*)(base + 75*MBc);         // m4 (v1 dead)
  float* outv = (float*)(base + 75*MBc);         // heads (o4 dead)
  // ---- persistent tail [78,84M) ----
  double* inv_an64 = (double*)(base + 78*MBc);               // 400KB
  double* inv_fp64 = (double*)(base + 78*MBc + 512*1024);    // 8KB
  double* cand_sc64= (double*)(base + 79*MBc);               // 1.28MB
  int*    cand_id  = (int*)   (base + 81*MBc);               // 640KB
  int*    run_id   = (int*)   (base + 82*MBc);               // 40KB

  dim3 blk(256);
  auto gg = [](int M,int N){ return dim3((unsigned)((N+63)/64),(unsigned)((M+63)/64)); };
  auto ng = [](int M,int N){ return dim3((unsigned)(((size_t)M*N+255)/256)); };
  const size_t IW = (size_t)2304*768, OW = (size_t)768*768;
  const size_t VOFF = (size_t)1536*768, KOFF = (size_t)768*768;
  const int* NORIDX = nullptr;
  const double* NOS = nullptr;

  // ======== phase 1: selection chain, all f64 ========
  prep64_k<<<ng(B_,D_), blk, 0, stream>>>(vis, fusedin64);
  dgemm_k<1,1,0><<<gg(B_,D_), blk, 0, stream>>>(vis, vqa_in_w, VOFF, vqa_in_b, 1536, attn_v64, NOS, NOS, B_, D_, D_, D_);
  dgemm_k<0,1,0><<<gg(B_,D_), blk, 0, stream>>>(attn_v64, vqa_out_w, 0, vqa_out_b, 0, fusedin64+D_, NOS, NOS, B_, D_, D_, 2*D_);
  dgemm_k<0,1,0><<<gg(B_,D_), blk, 0, stream>>>(fusedin64, fproj_w, 0, fproj_b, 0, ta64, NOS, NOS, B_, D_, 2*D_, D_);
  ln64_k<<<B_, blk, 0, stream>>>(ta64, fln_g, fln_b, fused64);
  dgemm_k<0,1,0><<<gg(B_,D_), blk, 0, stream>>>(fused64, sim_w, 0, sim_b, 0, fproj64, NOS, NOS, B_, D_, D_, D_);
  rnorm64_k<1><<<N_, blk, 0, stream>>>(ans, inv_an64);
  rnorm64_k<0><<<B_, blk, 0, stream>>>(fproj64, inv_fp64);
  for (int c=0;c<NCH_;++c){
    dgemm_k<0,0,1><<<gg(B_,CH_), blk, 0, stream>>>(fproj64, ans, (size_t)c*CH_*D_, nullptr, 0, sim64, inv_fp64, inv_an64 + c*CH_, B_, CH_, D_, CH_);
    topk10_chunk64_k<<<B_, blk, 0, stream>>>(sim64, cand_sc64, cand_id, c*CH_, c, CH_, CH_);
  }
  topk_final64_k<<<(B_+255)/256, blk, 0, stream>>>(cand_sc64, cand_id, run_id);

  // ======== phase 2: residual stream (f32) ========
  gemm_k<2,1><<<gg(B_,D_), blk, 0, stream>>>(vis, NORIDX, m_in_w, 0*IW+VOFF, m_in_b, 0*2304+1536, ta, B_, D_, D_, D_);
  gemm_k<0,1><<<gg(B_,D_), blk, 0, stream>>>(ta, NORIDX, m_out_w, 0*OW, m_out_b, 0*768, tb, B_, D_, D_, D_);
  ln_k<2><<<B_, blk, 0, stream>>>(tb, nullptr, vis, ln_g, ln_b, 0*D_, v1);
  gemm_k<2,1><<<gg(B_,D_), blk, 0, stream>>>(txt, NORIDX, m_in_w, 1*IW+VOFF, m_in_b, 1*2304+1536, ta, B_, D_, D_, D_);
  gemm_k<0,1><<<gg(B_,D_), blk, 0, stream>>>(ta, NORIDX, m_out_w, 1*OW, m_out_b, 1*768, tb, B_, D_, D_, D_);
  ln_k<2><<<B_, blk, 0, stream>>>(tb, nullptr, txt, ln_g, ln_b, 1*D_, t1);
  gemm_k<0,1><<<gg(B_,D_), blk, 0, stream>>>(t1, NORIDX, m_in_w, 2*IW+VOFF, m_in_b, 2*2304+1536, ta, B_, D_, D_, D_);
  gemm_k<0,1><<<gg(B_,D_), blk, 0, stream>>>(ta, NORIDX, m_out_w, 2*OW, m_out_b, 2*768, tb, B_, D_, D_, D_);
  gemm_k<0,1><<<gg(B_,D_), blk, 0, stream>>>(v1, NORIDX, m_in_w, 3*IW+VOFF, m_in_b, 3*2304+1536, tc, B_, D_, D_, D_);
  gemm_k<0,1><<<gg(B_,D_), blk, 0, stream>>>(tc, NORIDX, m_out_w, 3*OW, m_out_b, 3*768, td, B_, D_, D_, D_);
  ln_k<1><<<B_, blk, 0, stream>>>(tb, td, nullptr, ln_g, ln_b, 2*D_, fz0);
  // m4 over top-10 ans rows (gathered in-GEMM via run_id)
  gemm_k<0,1><<<gg(B_,D_), blk, 0, stream>>>(fz0, NORIDX, m_in_w, 4*IW, m_in_b, 4*2304, qh, B_, D_, D_, D_);
  gemm_k<3,1><<<gg(B_*K_,D_), blk, 0, stream>>>(ans, run_id, m_in_w, 4*IW+KOFF, m_in_b, 4*2304+768, kh, B_*K_, D_, D_, D_);
  gemm_k<3,1><<<gg(B_*K_,D_), blk, 0, stream>>>(ans, run_id, m_in_w, 4*IW+VOFF, m_in_b, 4*2304+1536, vh, B_*K_, D_, D_, D_);
  attn2_k<<<(B_*8+63)/64, dim3(64), 0, stream>>>(qh, kh, vh, o4);
  gemm_k<0,1><<<gg(B_,D_), blk, 0, stream>>>(o4, NORIDX, m_out_w, 4*OW, m_out_b, 4*768, ta, B_, D_, D_, D_);
  ln_k<1><<<B_, blk, 0, stream>>>(fz0, ta, nullptr, ln_g, ln_b, 3*D_, fz);
  // FFN + heads
  gemm_k<0,2><<<gg(B_,4*D_), blk, 0, stream>>>(fz, NORIDX, ffn_w1, 0, ffn_b1, 0, h1, B_, 4*D_, D_, 4*D_);
  gemm_k<0,1><<<gg(B_,D_), blk, 0, stream>>>(h1, NORIDX, ffn_w2, 0, ffn_b2, 0, tb, B_, D_, 4*D_, D_);
  add_k<<<ng(B_,D_), blk, 0, stream>>>(fz, tb, ta, B_*D_);
  gemm_k<0,1><<<gg(B_,D_), blk, 0, stream>>>(ta, NORIDX, outp_w, 0, outp_b, 0, outv, B_, D_, D_, D_);
  gemm_k<0,2><<<gg(B_,D_), blk, 0, stream>>>(outv, NORIDX, open_w1, 0, open_b1, 0, g1, B_, D_, D_, D_);
  gemm_k<0,1><<<gg(B_,N_), blk, 0, stream>>>(g1, NORIDX, open_w2, 0, open_b2, 0, (float*)d_out, B_, N_, D_, N_);
}